// Round 1
// baseline (133.453 us; speedup 1.0000x reference)
//
#include <hip/hip_runtime.h>
#include <math.h>

// GEBLNet via Gram-matrix reduction.
// R18 = R17 with LDS cut 10240->8192 B to lift the occupancy cap 12->16
// waves/CU (measured 37.5% occupancy == floor(128KiB/10240) exactly; VALU
// issue at 55% was latency-starved at 3 waves/SIMD).
//   (a) WeT removed: 2a reads We rows from row-major WeGV with stride-10
//       ds_read_b64; address depends only on jk -> 9 distinct addrs over 18
//       banks, 7-lane broadcast each: conflict-free. (-1008 B, -WeT stores)
//   (b) Bs rows pad 10->9 (exact). Store: consecutive lanes, consecutive
//       float2 (2-way, free). 2b read: banks uu*10+2k -> max 2-way. (-624 B)
//   (c) Phase-3+ scratch (Tpar/tr1/sc1/gb/tra) union-overlaid into Bs
//       (dead after 2b; g-loop syncthreads fences reuse). (-720 B)
// Shape (R10/R14-proven): 8192 blocks x 64 threads, 1 wave = 1 point.
//   2a: job=(uu,v,jk): B[uu,v,jk] = sum_w w1[u0+uu,v,w]*We[w,jk]
//   2b: H[u0+uu,ik] = sum_{v,j} We[v,i,j]*B[uu,v,j*3+k]  (54 jobs, 39 cmacs)
// LESSON (R16): merging the two passes pushes VGPR 44->84 (compiler pipelines
// the longer job loop) and loses occupancy — keep the two-pass shape.
// LESSON (R13/R16): VGPR>64 is the occupancy cliff; keep per-job state tiny.
// LESSON (R15): fine-grained 1-cmac jobs beat wider jobs.
// LESSON (R12): multi-wave blocks regress. LESSON (R11): direct-w2
// contraction regresses. LESSON (R4+R7): launch_bounds min-waves arg ->
// spill. LESSON (R6): never reinterpret-cast local arrays.

#define NPTS 8192
#define THRESH 0.001f

__global__ void geblnet_setup(const float* __restrict__ w2,
                              float4* __restrict__ CTt) {
    int j = blockIdx.x * blockDim.x + threadIdx.x;
    if (j >= 12 * 169) return;
    int u = j / 169, it = j % 169;
    const float* W = w2 + u * 25 * 25 * 2;
#define WR(v, w) W[((v) * 25 + (w)) * 2]
#define WI(v, w) W[((v) * 25 + (w)) * 2 + 1]
    float c0, c1, c2, c3;
    if (it < 78) {                       // S pairs, a<=b
        int q = it, a = 0;
        while (q >= 12 - a) { q -= 12 - a; ++a; }
        int b = a + q;
        float ar = WR(a, b) + (a != b ? WR(b, a) : 0.f);
        float ai = WI(a, b) + (a != b ? WI(b, a) : 0.f);
        float br = WR(12 + a, 12 + b) + (a != b ? WR(12 + b, 12 + a) : 0.f);
        float bi = WI(12 + a, 12 + b) + (a != b ? WI(12 + b, 12 + a) : 0.f);
        c0 = ar + br; c1 = bi - ai; c2 = ai + bi; c3 = ar - br;
    } else if (it < 156) {               // Hm pairs, a<=b
        int q = it - 78, a = 0;
        while (q >= 12 - a) { q -= 12 - a; ++a; }
        int b = a + q;
        if (a != b) {
            float gr = WR(a, 12 + b) + WR(12 + b, a);
            float gi = WI(a, 12 + b) + WI(12 + b, a);
            float dr = WR(b, 12 + a) + WR(12 + a, b);
            float di = WI(b, 12 + a) + WI(12 + a, b);
            c0 = gr + dr; c1 = di - gi; c2 = gi + di; c3 = gr - dr;
        } else {
            float er = WR(a, 12 + a) + WR(12 + a, a);
            float ei = WI(a, 12 + a) + WI(12 + a, a);
            c0 = er; c1 = 0.f; c2 = ei; c3 = 0.f;
        }
    } else if (it < 168) {               // trace terms
        int a = it - 156;
        float fr = WR(a, 24) + WR(24, a), fi = WI(a, 24) + WI(24, a);
        float pr = WR(12 + a, 24) + WR(24, 12 + a);
        float pi = WI(12 + a, 24) + WI(24, 12 + a);
        c0 = fr + pr; c1 = pi - fi; c2 = fi + pi; c3 = fr - pr;
    } else {                             // unit-unit
        c0 = 3.f * WR(24, 24); c1 = 0.f; c2 = 3.f * WI(24, 24); c3 = 0.f;
    }
    CTt[it * 12 + u] = make_float4(c0, c1, c2, c3);
#undef WR
#undef WI
}

// Scratch union: Bs is dead after phase 2b; phase-3..6 scratch reuses it.
union Scr {
    float2 bs[702];                     // B[uu][v][jk], rows exact 9 (5616 B)
    struct {
        float2 tpar[60];                // phase 5 partials
        float2 tr1[12];                 // traces (layer 1, reused layer 2)
        float  sc1[12];                 // combined gerelu+trnorm scale
        float  gb[12];
        float  tra[12];
    } s;
};

__global__ __launch_bounds__(64) void geblnet_main(
    const float2* __restrict__ x2,      // (8192, 10, 9) complex
    const float2* __restrict__ w1g,     // (12,13,13) complex
    const float* __restrict__ dw,       // (24,)
    const float* __restrict__ db,       // (1,)
    const float4* __restrict__ CTt,     // (169,12)
    float* __restrict__ out)            // (8192,)
{
    // Overlay: phases 1-2 = We row-major (13 ch incl. identity, stride 10);
    //          phases 4-5 = GV[169].
    __shared__ float2 WeGV[170];        // 1360 B
    __shared__ Scr S;                   // 5616 B
    __shared__ float2 Hs[108];          //  864 B
    // total 7840 B -> 8192 alloc -> 16 blocks/CU

    const int t = threadIdx.x;
    const int p = blockIdx.x;

    // ---- phase 1: build We channels 0..12, row-major only
    for (int j = t; j < 117; j += 64) {
        int v = j / 9, ik = j - v * 9;
        int i = ik / 3, jj = ik - i * 3;
        float2 val;
        if (v < 6) val = x2[(size_t)p * 90 + (4 + v) * 9 + ik];
        else if (v < 12) {
            float2 s = x2[(size_t)p * 90 + (v - 2) * 9 + jj * 3 + i];
            val = make_float2(s.x, -s.y);
        } else val = make_float2((i == jj) ? 1.f : 0.f, 0.f);
        WeGV[v * 10 + ik] = val;
    }
    __syncthreads();

    // ---- phase 2: layer 1 on all 64 lanes, two u-half passes
    #pragma unroll 1
    for (int g = 0; g < 2; ++g) {
        const int u0 = g * 6;
        // 2a: B[uu][v][jk] = sum_w w1[u0+uu,v,w] * We[w][jk]
        //     We read is per-w broadcast (addr depends only on jk): no
        //     bank conflicts, and no transposed copy needed.
        #pragma unroll 1
        for (int e = t; e < 702; e += 64) {
            int uu = e / 117, rem = e - uu * 117;
            int v = rem / 9, jk = rem - v * 9;
            const float2* cp = w1g + ((u0 + uu) * 13 + v) * 13;   // contiguous
            float br = 0.f, bi = 0.f;
            #pragma unroll
            for (int w = 0; w < 13; ++w) {
                float2 cc = cp[w];
                float2 ee = WeGV[w * 10 + jk];
                br += cc.x * ee.x - cc.y * ee.y;
                bi += cc.x * ee.y + cc.y * ee.x;
            }
            S.bs[(uu * 13 + v) * 9 + jk] = make_float2(br, bi);
        }
        __syncthreads();
        // 2b: H[u0+uu][i][k] = sum_{v,j} We[v][i][j] * B[uu][v][j*3+k]
        if (t < 54) {
            int uu = t / 9, ik = t - uu * 9;
            int i = ik / 3, k = ik - i * 3;
            float hr = 0.f, hi = 0.f;
            #pragma unroll
            for (int v = 0; v < 13; ++v) {
                const float2* a = &WeGV[v * 10 + i * 3];
                const float2* b = &S.bs[(uu * 13 + v) * 9 + k];
                #pragma unroll
                for (int j = 0; j < 3; ++j) {
                    float2 aj = a[j];
                    float2 bj = b[j * 3];
                    hr += aj.x * bj.x - aj.y * bj.y;
                    hi += aj.x * bj.y + aj.y * bj.x;
                }
            }
            Hs[(u0 + uu) * 9 + ik] = make_float2(hr, hi);
        }
        __syncthreads();
    }

    // ---- phase 3: traces + gerelu + trnorm scales (Bs dead; union scratch)
    if (t < 12) {
        float2 a = Hs[t * 9 + 0], b = Hs[t * 9 + 4], c = Hs[t * 9 + 8];
        float2 tt = make_float2(a.x + b.x + c.x, a.y + b.y + c.y);
        S.s.tr1[t] = tt;
        float gg = tt.x > 0.f ? tt.x : 0.f;
        S.s.gb[t] = gg;
        S.s.tra[t] = gg * sqrtf(tt.x * tt.x + tt.y * tt.y);
    }
    __syncthreads();
    if (t < 12) {
        float m = 0.f;
        #pragma unroll
        for (int u = 0; u < 12; ++u) m += S.s.tra[u];
        S.s.sc1[t] = S.s.gb[t] / fmaxf(m * (1.f / 12.f), THRESH);
    }
    __syncthreads();

    // ---- phase 4: Gram values -> GV (overlays We row-major; dead now)
    for (int it = t; it < 169; it += 64) {
        float2 val;
        if (it < 156) {
            int q = it < 78 ? it : it - 78;
            float fs = sqrtf(625.0f - 8.0f * (float)q);   // exact at bucket edges
            int a = (int)((25.0f - fs) * 0.5f);
            int b = q - (a * (25 - a)) / 2 + a;
            const float2* Ha = &Hs[a * 9];
            const float2* Hb = &Hs[b * 9];
            float s = S.s.sc1[a] * S.s.sc1[b];
            float vr = 0.f, vi = 0.f;
            if (it < 78) {                    // S = tr(Aa Ab)
                #pragma unroll
                for (int i = 0; i < 3; ++i)
                    #pragma unroll
                    for (int jj = 0; jj < 3; ++jj) {
                        float2 A = Ha[i * 3 + jj], B = Hb[jj * 3 + i];
                        vr += A.x * B.x - A.y * B.y;
                        vi += A.x * B.y + A.y * B.x;
                    }
            } else {                          // Hm = tr(Aa Ab^H)
                #pragma unroll
                for (int e = 0; e < 9; ++e) {
                    float2 A = Ha[e], B = Hb[e];
                    vr += A.x * B.x + A.y * B.y;
                    vi += A.y * B.x - A.x * B.y;
                }
            }
            val = make_float2(s * vr, s * vi);
        } else if (it < 168) {
            int a = it - 156;
            float s = S.s.sc1[a]; float2 tt = S.s.tr1[a];
            val = make_float2(s * tt.x, s * tt.y);
        } else {
            val = make_float2(1.f, 0.f);
        }
        WeGV[it] = val;
    }
    __syncthreads();

    // ---- phase 5: coefficient contraction, lane=(q,u), 60 active
    if (t < 60) {
        int q = t / 12, u = t - q * 12;
        int i0 = q * 34, i1 = (q == 4) ? 169 : i0 + 34;
        float tre = 0.f, tim = 0.f;
        for (int it = i0; it < i1; ++it) {
            float4 c = CTt[it * 12 + u];
            float2 gv = WeGV[it];
            tre += c.x * gv.x + c.y * gv.y;
            tim += c.z * gv.x + c.w * gv.y;
        }
        S.s.tpar[u * 5 + q] = make_float2(tre, tim);
    }
    __syncthreads();

    // ---- phase 6: layer-2 gerelu + trnorm + dense head
    if (t < 12) {
        float2 tt = make_float2(0.f, 0.f);
        #pragma unroll
        for (int q = 0; q < 5; ++q) {
            float2 A = S.s.tpar[t * 5 + q];
            tt.x += A.x; tt.y += A.y;
        }
        S.s.tr1[t] = tt;
        float g = tt.x > 0.f ? tt.x : 0.f;
        S.s.gb[t] = g;
        S.s.tra[t] = g * sqrtf(tt.x * tt.x + tt.y * tt.y);
    }
    __syncthreads();
    if (t == 0) {
        float m = 0.f;
        #pragma unroll
        for (int u = 0; u < 12; ++u) m += S.s.tra[u];
        float inv = 1.f / fmaxf(m * (1.f / 12.f), THRESH);
        float acc = db[0];
        #pragma unroll
        for (int u = 0; u < 12; ++u) {
            float s = S.s.gb[u] * inv * (1.f / 3.f);
            acc += s * (S.s.tr1[u].x * dw[2 * u] + S.s.tr1[u].y * dw[2 * u + 1]);
        }
        out[p] = acc;
    }
}

extern "C" void kernel_launch(void* const* d_in, const int* in_sizes, int n_in,
                              void* d_out, int out_size, void* d_ws, size_t ws_size,
                              hipStream_t stream) {
    const float* x  = (const float*)d_in[0];
    const float* w1 = (const float*)d_in[1];
    const float* w2 = (const float*)d_in[2];
    const float* dw = (const float*)d_in[3];
    const float* db = (const float*)d_in[4];
    float* outp = (float*)d_out;
    float4* CTt = (float4*)d_ws;          // 12*169*16 B = 32448 B

    geblnet_setup<<<(12 * 169 + 255) / 256, 256, 0, stream>>>(w2, CTt);

    geblnet_main<<<NPTS, 64, 0, stream>>>(
        (const float2*)x, (const float2*)w1, dw, db, CTt, outp);
}

// Round 2
// 125.044 us; speedup vs baseline: 1.0672x; 1.0672x over previous
//
#include <hip/hip_runtime.h>
#include <math.h>

// GEBLNet via Gram-matrix reduction.
// R19 = R18 + ILP: occupancy is pinned at ~11.5 waves/CU by an unknown
// non-LDS, non-VGPR resource (R17 floor(P/10240)=12 and R18 floor(P/8192)=12
// have no common LDS pool P -> LDS is not the cap; VGPR=44 caps nothing).
// With TLP capped at ~3 waves/SIMD, attack per-wave latency instead:
//   (a) 2a e-loop unroll 2: two jobs' 13+13 load batches in flight.
//   (b) 2a /117 replaced by incremental (uu,rem) update (t<117 -> uu=0).
//   (c) phase-5 unroll 4: 4 CTt/GV load pairs in flight (was a ~34x200cy
//       serial latency chain -- largest single per-wave chunk).
// R18 lessons: LDS 8192B, bank conflicts 2.74M->98K (fix fully explained the
// -4.7us); union overlay of Bs/scratch is sound.
// Shape (R10/R14-proven): 8192 blocks x 64 threads, 1 wave = 1 point.
// LESSON (R16): full merge of 2a+2b pushes VGPR 44->84 -> regress; unroll 2
// is the mild form, watch VGPR<=~70.
// LESSON (R15): fine-grained 1-cmac jobs beat wider jobs.
// LESSON (R12): multi-wave blocks regress. LESSON (R11): direct-w2
// contraction regresses. LESSON (R4+R7): launch_bounds min-waves arg ->
// spill. LESSON (R6): never reinterpret-cast local arrays.

#define NPTS 8192
#define THRESH 0.001f

__global__ void geblnet_setup(const float* __restrict__ w2,
                              float4* __restrict__ CTt) {
    int j = blockIdx.x * blockDim.x + threadIdx.x;
    if (j >= 12 * 169) return;
    int u = j / 169, it = j % 169;
    const float* W = w2 + u * 25 * 25 * 2;
#define WR(v, w) W[((v) * 25 + (w)) * 2]
#define WI(v, w) W[((v) * 25 + (w)) * 2 + 1]
    float c0, c1, c2, c3;
    if (it < 78) {                       // S pairs, a<=b
        int q = it, a = 0;
        while (q >= 12 - a) { q -= 12 - a; ++a; }
        int b = a + q;
        float ar = WR(a, b) + (a != b ? WR(b, a) : 0.f);
        float ai = WI(a, b) + (a != b ? WI(b, a) : 0.f);
        float br = WR(12 + a, 12 + b) + (a != b ? WR(12 + b, 12 + a) : 0.f);
        float bi = WI(12 + a, 12 + b) + (a != b ? WI(12 + b, 12 + a) : 0.f);
        c0 = ar + br; c1 = bi - ai; c2 = ai + bi; c3 = ar - br;
    } else if (it < 156) {               // Hm pairs, a<=b
        int q = it - 78, a = 0;
        while (q >= 12 - a) { q -= 12 - a; ++a; }
        int b = a + q;
        if (a != b) {
            float gr = WR(a, 12 + b) + WR(12 + b, a);
            float gi = WI(a, 12 + b) + WI(12 + b, a);
            float dr = WR(b, 12 + a) + WR(12 + a, b);
            float di = WI(b, 12 + a) + WI(12 + a, b);
            c0 = gr + dr; c1 = di - gi; c2 = gi + di; c3 = gr - dr;
        } else {
            float er = WR(a, 12 + a) + WR(12 + a, a);
            float ei = WI(a, 12 + a) + WI(12 + a, a);
            c0 = er; c1 = 0.f; c2 = ei; c3 = 0.f;
        }
    } else if (it < 168) {               // trace terms
        int a = it - 156;
        float fr = WR(a, 24) + WR(24, a), fi = WI(a, 24) + WI(24, a);
        float pr = WR(12 + a, 24) + WR(24, 12 + a);
        float pi = WI(12 + a, 24) + WI(24, 12 + a);
        c0 = fr + pr; c1 = pi - fi; c2 = fi + pi; c3 = fr - pr;
    } else {                             // unit-unit
        c0 = 3.f * WR(24, 24); c1 = 0.f; c2 = 3.f * WI(24, 24); c3 = 0.f;
    }
    CTt[it * 12 + u] = make_float4(c0, c1, c2, c3);
#undef WR
#undef WI
}

// Scratch union: Bs is dead after phase 2b; phase-3..6 scratch reuses it.
union Scr {
    float2 bs[702];                     // B[uu][v][jk], rows exact 9 (5616 B)
    struct {
        float2 tpar[60];                // phase 5 partials
        float2 tr1[12];                 // traces (layer 1, reused layer 2)
        float  sc1[12];                 // combined gerelu+trnorm scale
        float  gb[12];
        float  tra[12];
    } s;
};

__global__ __launch_bounds__(64) void geblnet_main(
    const float2* __restrict__ x2,      // (8192, 10, 9) complex
    const float2* __restrict__ w1g,     // (12,13,13) complex
    const float* __restrict__ dw,       // (24,)
    const float* __restrict__ db,       // (1,)
    const float4* __restrict__ CTt,     // (169,12)
    float* __restrict__ out)            // (8192,)
{
    // Overlay: phases 1-2 = We row-major (13 ch incl. identity, stride 10);
    //          phases 4-5 = GV[169].
    __shared__ float2 WeGV[170];        // 1360 B
    __shared__ Scr S;                   // 5616 B
    __shared__ float2 Hs[108];          //  864 B
    // total 7840 B -> 8192 alloc

    const int t = threadIdx.x;
    const int p = blockIdx.x;

    // ---- phase 1: build We channels 0..12, row-major only
    for (int j = t; j < 117; j += 64) {
        int v = j / 9, ik = j - v * 9;
        int i = ik / 3, jj = ik - i * 3;
        float2 val;
        if (v < 6) val = x2[(size_t)p * 90 + (4 + v) * 9 + ik];
        else if (v < 12) {
            float2 s = x2[(size_t)p * 90 + (v - 2) * 9 + jj * 3 + i];
            val = make_float2(s.x, -s.y);
        } else val = make_float2((i == jj) ? 1.f : 0.f, 0.f);
        WeGV[v * 10 + ik] = val;
    }
    __syncthreads();

    // ---- phase 2: layer 1 on all 64 lanes, two u-half passes
    #pragma unroll 1
    for (int g = 0; g < 2; ++g) {
        const int u0 = g * 6;
        // 2a: B[uu][v][jk] = sum_w w1[u0+uu,v,w] * We[w][jk]
        //     We read is per-w broadcast (addr depends only on jk): no
        //     bank conflicts. Incremental (uu,rem): e starts at t<117.
        {
            int uu = 0, rem = t;
            #pragma unroll 2
            for (int e = t; e < 702; e += 64) {
                int v = rem / 9, jk = rem - v * 9;
                const float2* cp = w1g + ((u0 + uu) * 13 + v) * 13; // contiguous
                float br = 0.f, bi = 0.f;
                #pragma unroll
                for (int w = 0; w < 13; ++w) {
                    float2 cc = cp[w];
                    float2 ee = WeGV[w * 10 + jk];
                    br += cc.x * ee.x - cc.y * ee.y;
                    bi += cc.x * ee.y + cc.y * ee.x;
                }
                S.bs[(uu * 13 + v) * 9 + jk] = make_float2(br, bi);
                rem += 64;
                if (rem >= 117) { rem -= 117; ++uu; }
            }
        }
        __syncthreads();
        // 2b: H[u0+uu][i][k] = sum_{v,j} We[v][i][j] * B[uu][v][j*3+k]
        if (t < 54) {
            int uu = t / 9, ik = t - uu * 9;
            int i = ik / 3, k = ik - i * 3;
            float hr = 0.f, hi = 0.f;
            #pragma unroll
            for (int v = 0; v < 13; ++v) {
                const float2* a = &WeGV[v * 10 + i * 3];
                const float2* b = &S.bs[(uu * 13 + v) * 9 + k];
                #pragma unroll
                for (int j = 0; j < 3; ++j) {
                    float2 aj = a[j];
                    float2 bj = b[j * 3];
                    hr += aj.x * bj.x - aj.y * bj.y;
                    hi += aj.x * bj.y + aj.y * bj.x;
                }
            }
            Hs[(u0 + uu) * 9 + ik] = make_float2(hr, hi);
        }
        __syncthreads();
    }

    // ---- phase 3: traces + gerelu + trnorm scales (Bs dead; union scratch)
    if (t < 12) {
        float2 a = Hs[t * 9 + 0], b = Hs[t * 9 + 4], c = Hs[t * 9 + 8];
        float2 tt = make_float2(a.x + b.x + c.x, a.y + b.y + c.y);
        S.s.tr1[t] = tt;
        float gg = tt.x > 0.f ? tt.x : 0.f;
        S.s.gb[t] = gg;
        S.s.tra[t] = gg * sqrtf(tt.x * tt.x + tt.y * tt.y);
    }
    __syncthreads();
    if (t < 12) {
        float m = 0.f;
        #pragma unroll
        for (int u = 0; u < 12; ++u) m += S.s.tra[u];
        S.s.sc1[t] = S.s.gb[t] / fmaxf(m * (1.f / 12.f), THRESH);
    }
    __syncthreads();

    // ---- phase 4: Gram values -> GV (overlays We row-major; dead now)
    for (int it = t; it < 169; it += 64) {
        float2 val;
        if (it < 156) {
            int q = it < 78 ? it : it - 78;
            float fs = sqrtf(625.0f - 8.0f * (float)q);   // exact at bucket edges
            int a = (int)((25.0f - fs) * 0.5f);
            int b = q - (a * (25 - a)) / 2 + a;
            const float2* Ha = &Hs[a * 9];
            const float2* Hb = &Hs[b * 9];
            float s = S.s.sc1[a] * S.s.sc1[b];
            float vr = 0.f, vi = 0.f;
            if (it < 78) {                    // S = tr(Aa Ab)
                #pragma unroll
                for (int i = 0; i < 3; ++i)
                    #pragma unroll
                    for (int jj = 0; jj < 3; ++jj) {
                        float2 A = Ha[i * 3 + jj], B = Hb[jj * 3 + i];
                        vr += A.x * B.x - A.y * B.y;
                        vi += A.x * B.y + A.y * B.x;
                    }
            } else {                          // Hm = tr(Aa Ab^H)
                #pragma unroll
                for (int e = 0; e < 9; ++e) {
                    float2 A = Ha[e], B = Hb[e];
                    vr += A.x * B.x + A.y * B.y;
                    vi += A.y * B.x - A.x * B.y;
                }
            }
            val = make_float2(s * vr, s * vi);
        } else if (it < 168) {
            int a = it - 156;
            float s = S.s.sc1[a]; float2 tt = S.s.tr1[a];
            val = make_float2(s * tt.x, s * tt.y);
        } else {
            val = make_float2(1.f, 0.f);
        }
        WeGV[it] = val;
    }
    __syncthreads();

    // ---- phase 5: coefficient contraction, lane=(q,u), 60 active
    //      unroll 4 -> 4 CTt/GV load pairs in flight (was serial latency).
    if (t < 60) {
        int q = t / 12, u = t - q * 12;
        int i0 = q * 34, i1 = (q == 4) ? 169 : i0 + 34;
        float tre = 0.f, tim = 0.f;
        #pragma unroll 4
        for (int it = i0; it < i1; ++it) {
            float4 c = CTt[it * 12 + u];
            float2 gv = WeGV[it];
            tre += c.x * gv.x + c.y * gv.y;
            tim += c.z * gv.x + c.w * gv.y;
        }
        S.s.tpar[u * 5 + q] = make_float2(tre, tim);
    }
    __syncthreads();

    // ---- phase 6: layer-2 gerelu + trnorm + dense head
    if (t < 12) {
        float2 tt = make_float2(0.f, 0.f);
        #pragma unroll
        for (int q = 0; q < 5; ++q) {
            float2 A = S.s.tpar[t * 5 + q];
            tt.x += A.x; tt.y += A.y;
        }
        S.s.tr1[t] = tt;
        float g = tt.x > 0.f ? tt.x : 0.f;
        S.s.gb[t] = g;
        S.s.tra[t] = g * sqrtf(tt.x * tt.x + tt.y * tt.y);
    }
    __syncthreads();
    if (t == 0) {
        float m = 0.f;
        #pragma unroll
        for (int u = 0; u < 12; ++u) m += S.s.tra[u];
        float inv = 1.f / fmaxf(m * (1.f / 12.f), THRESH);
        float acc = db[0];
        #pragma unroll
        for (int u = 0; u < 12; ++u) {
            float s = S.s.gb[u] * inv * (1.f / 3.f);
            acc += s * (S.s.tr1[u].x * dw[2 * u] + S.s.tr1[u].y * dw[2 * u + 1]);
        }
        out[p] = acc;
    }
}

extern "C" void kernel_launch(void* const* d_in, const int* in_sizes, int n_in,
                              void* d_out, int out_size, void* d_ws, size_t ws_size,
                              hipStream_t stream) {
    const float* x  = (const float*)d_in[0];
    const float* w1 = (const float*)d_in[1];
    const float* w2 = (const float*)d_in[2];
    const float* dw = (const float*)d_in[3];
    const float* db = (const float*)d_in[4];
    float* outp = (float*)d_out;
    float4* CTt = (float4*)d_ws;          // 12*169*16 B = 32448 B

    geblnet_setup<<<(12 * 169 + 255) / 256, 256, 0, stream>>>(w2, CTt);

    geblnet_main<<<NPTS, 64, 0, stream>>>(
        (const float2*)x, (const float2*)w1, dw, db, CTt, outp);
}